// Round 8
// baseline (529.003 us; speedup 1.0000x reference)
//
#include <hip/hip_runtime.h>
#include <hip/hip_bf16.h>
#include <math.h>

#define BS   4096   // B*S
#define HH   4096   // hidden
#define NH   32
#define NG   8
#define HD   128
#define SEQ  2048
#define NQKV 6144   // H + 2*NG*HD

typedef float f32x4 __attribute__((ext_vector_type(4)));
typedef float f32x16 __attribute__((ext_vector_type(16)));
typedef short s16x8 __attribute__((ext_vector_type(8)));
typedef short s16x4 __attribute__((ext_vector_type(4)));
typedef unsigned int u32x4 __attribute__((ext_vector_type(4)));

__device__ __forceinline__ unsigned short f2bf(float f) {
  unsigned int u = __builtin_bit_cast(unsigned int, f);
  unsigned int r = (u + 0x7fffu + ((u >> 16) & 1u)) >> 16;
  return (unsigned short)r;
}
__device__ __forceinline__ float b2f(short h) {
  unsigned int u = ((unsigned int)(unsigned short)h) << 16;
  return __builtin_bit_cast(float, u);
}

// async global->LDS, 16B per lane; lds base must be wave-uniform (HW adds lane*16)
__device__ __forceinline__ void gload16(const void* g, void* l) {
  __builtin_amdgcn_global_load_lds((__attribute__((address_space(1))) void*)(g),
                                   (__attribute__((address_space(3))) void*)(l), 16, 0, 0);
}

#define BARRIER __builtin_amdgcn_s_barrier()
#define PRIO1 __builtin_amdgcn_s_setprio(1)
#define PRIO0 __builtin_amdgcn_s_setprio(0)

// ---------------- cast fp32 -> bf16 (vectorized) ----------------
__global__ void cast_f32_bf16(const float* __restrict__ in, short* __restrict__ out, long n4) {
  long i = (long)blockIdx.x * blockDim.x + threadIdx.x;
  long stride = (long)gridDim.x * blockDim.x;
  for (; i < n4; i += stride) {
    float4 v = *(const float4*)&in[i * 4];
    s16x4 o;
    o[0] = (short)f2bf(v.x); o[1] = (short)f2bf(v.y);
    o[2] = (short)f2bf(v.z); o[3] = (short)f2bf(v.w);
    *(s16x4*)&out[i * 4] = o;
  }
}

// ---------------- transpose + cast: in f32 [R][C] -> out bf16 [C][R] ----------------
__global__ __launch_bounds__(256) void transpose_cast(const float* __restrict__ in,
                                                      short* __restrict__ out, int R, int C) {
  __shared__ float tile[32][33];
  int tx = threadIdx.x & 31, ty = threadIdx.x >> 5;  // ty 0..7
  long c0 = (long)blockIdx.x * 32, r0 = (long)blockIdx.y * 32;
#pragma unroll
  for (int j = 0; j < 32; j += 8)
    tile[ty + j][tx] = in[(r0 + ty + j) * C + c0 + tx];
  __syncthreads();
  int q = threadIdx.x & 7;    // 8 quads -> 32 R-cols
  int jj = threadIdx.x >> 3;  // 32 output rows
  s16x4 o;
  o[0] = (short)f2bf(tile[4 * q + 0][jj]);
  o[1] = (short)f2bf(tile[4 * q + 1][jj]);
  o[2] = (short)f2bf(tile[4 * q + 2][jj]);
  o[3] = (short)f2bf(tile[4 * q + 3][jj]);
  *(s16x4*)&out[(c0 + jj) * R + r0 + 4 * q] = o;
}

// ================= 256x256 8-phase GEMM (R4 schedule: proven best, 128.6us) =================
// FROZEN (control). R5 deep-staging and R2 flattening both regressed; this is the
// local optimum (~46 MfmaUtil). Gray-code quadrants, staging AU0+BU0@p1, BU1@p2,
// AU1@p3, waits vmcnt(6)/vmcnt(6)/-/vmcnt(4). setprio kept (8-phase: T5-positive).
#define LDA_FR(BASE, DB)                                                         \
  {                                                                              \
    _Pragma("unroll") for (int mf = 0; mf < 4; ++mf)                             \
      _Pragma("unroll") for (int ks = 0; ks < 2; ++ks)                           \
        af[mf][ks] = *(const s16x8*)&lds[(BASE) + (DB) * 8192 + aoff[mf][ks]];   \
  }
#define LDB_FR(BASE, DB)                                                         \
  {                                                                              \
    _Pragma("unroll") for (int nf = 0; nf < 2; ++nf)                             \
      _Pragma("unroll") for (int ks = 0; ks < 2; ++ks)                           \
        bf[nf][ks] = *(const s16x8*)&lds[(BASE) + (DB) * 8192 + boff[nf][ks]];   \
  }
#define MF_Q(MS, NS)                                                             \
  {                                                                              \
    _Pragma("unroll") for (int ks = 0; ks < 2; ++ks)                             \
      _Pragma("unroll") for (int mf = 0; mf < 4; ++mf)                           \
        _Pragma("unroll") for (int nf = 0; nf < 2; ++nf)                         \
          acc[(MS) * 4 + mf][(NS) * 2 + nf] = __builtin_amdgcn_mfma_f32_16x16x32_bf16( \
              af[mf][ks], bf[nf][ks], acc[(MS) * 4 + mf][(NS) * 2 + nf], 0, 0, 0);     \
  }
#define STG_AU0(DB, KB) { gload16(sA0 + (KB), &lds[0 + (DB) * 8192 + du0]);            \
                          gload16(sA1 + (KB), &lds[0 + (DB) * 8192 + du1]); }
#define STG_BU0(DB, KB) { gload16(sB0 + (KB), &lds[32768 + (DB) * 8192 + du0]);        \
                          gload16(sB1 + (KB), &lds[32768 + (DB) * 8192 + du1]); }
#define STG_AU1(DB, KB) { gload16(sA0 + 64 * (long)K + (KB), &lds[16384 + (DB) * 8192 + du0]); \
                          gload16(sA1 + 64 * (long)K + (KB), &lds[16384 + (DB) * 8192 + du1]); }
#define STG_BU1(DB, KB) { gload16(sB0 + 32 * (long)K + (KB), &lds[49152 + (DB) * 8192 + du0]); \
                          gload16(sB1 + 32 * (long)K + (KB), &lds[49152 + (DB) * 8192 + du1]); }

#define TILE256(DB, KBS)                                                         \
  LDA_FR(0, DB); LDB_FR(32768, DB);                                              \
  STG_AU0(DB ^ 1, KBS); STG_BU0(DB ^ 1, KBS);                                    \
  BARRIER;                                                                       \
  PRIO1; MF_Q(0, 0); PRIO0;                                                      \
  asm volatile("s_waitcnt vmcnt(6)" ::: "memory");                               \
  BARRIER;                                                                       \
  LDB_FR(49152, DB);                                                             \
  STG_BU1(DB ^ 1, KBS);                                                          \
  BARRIER;                                                                       \
  PRIO1; MF_Q(0, 1); PRIO0;                                                      \
  asm volatile("s_waitcnt vmcnt(6)" ::: "memory");                               \
  BARRIER;                                                                       \
  LDA_FR(16384, DB);                                                             \
  STG_AU1(DB ^ 1, KBS);                                                          \
  BARRIER;                                                                       \
  PRIO1; MF_Q(1, 1); PRIO0;                                                      \
  BARRIER;                                                                       \
  LDB_FR(32768, DB);                                                             \
  BARRIER;                                                                       \
  PRIO1; MF_Q(1, 0); PRIO0;                                                      \
  asm volatile("s_waitcnt vmcnt(4)" ::: "memory");                               \
  BARRIER;

// MODE 0: plain f32 output, no bias (dense projection)
// MODE 2: fused rope-Q epilogue (N=4096 launch: all cols are Q; scaled, log2e folded)
template <int MODE>
__global__ __launch_bounds__(512, 1) void gemm256(const short* __restrict__ A,
                                                  const short* __restrict__ Bt,
                                                  const float* __restrict__ bias,
                                                  void* __restrict__ Cout,
                                                  const float* __restrict__ cache,
                                                  short* __restrict__ Qb,
                                                  int M, int N, int K) {
  extern __shared__ short lds[];
  const int t = threadIdx.x;
  const int lane = t & 63, w = t >> 6;
  const int g = lane >> 4, lr = lane & 15;
  const int wm = w >> 2, wn = w & 3;  // 2 x 4 wave grid
  const long bm = (long)blockIdx.y * 256;
  const long bn = (long)blockIdx.x * 256;

  const short *sA0, *sA1, *sB0, *sB1;
  {
    int c0 = t, c1 = t + 512;
    int h0 = c0 >> 9, r0 = (c0 >> 3) & 63, tc0 = (c0 & 7) ^ (r0 & 7);
    int h1 = c1 >> 9, r1 = (c1 >> 3) & 63, tc1 = (c1 & 7) ^ (r1 & 7);
    sA0 = A + (bm + h0 * 128 + r0) * (long)K + tc0 * 8;
    sA1 = A + (bm + h1 * 128 + r1) * (long)K + tc1 * 8;
    int g0 = c0 >> 8, rb0 = (c0 >> 3) & 31, tb0 = (c0 & 7) ^ (rb0 & 7);
    int g1 = c1 >> 8, rb1 = (c1 >> 3) & 31, tb1 = (c1 & 7) ^ (rb1 & 7);
    sB0 = Bt + (bn + g0 * 64 + rb0) * (long)K + tb0 * 8;
    sB1 = Bt + (bn + g1 * 64 + rb1) * (long)K + tb1 * 8;
  }
  const int du0 = w * 512;
  const int du1 = w * 512 + 4096;

  int aoff[4][2], boff[2][2];
#pragma unroll
  for (int mf = 0; mf < 4; ++mf)
#pragma unroll
    for (int ks = 0; ks < 2; ++ks)
      aoff[mf][ks] = wm * 4096 + (mf * 16 + lr) * 64 + (((ks * 4 + g) ^ (lr & 7)) * 8);
#pragma unroll
  for (int nf = 0; nf < 2; ++nf)
#pragma unroll
    for (int ks = 0; ks < 2; ++ks)
      boff[nf][ks] = wn * 2048 + (nf * 16 + lr) * 64 + (((ks * 4 + g) ^ (lr & 7)) * 8);

  f32x4 acc[8][4] = {};
  s16x8 af[4][2], bf[2][2];

  STG_AU0(0, 0); STG_BU0(0, 0); STG_AU1(0, 0); STG_BU1(0, 0);
  asm volatile("s_waitcnt vmcnt(0)" ::: "memory");
  BARRIER;

  const int NT = K >> 6;
  for (int kt = 0; kt < NT; kt += 2) {
    const long kb1 = (long)(kt + 1) * 64;
    const long kb2 = (kt + 2 < NT) ? (long)(kt + 2) * 64 : 0l;
    TILE256(0, kb1);
    TILE256(1, kb2);
  }

  if (MODE == 0) {
#pragma unroll
    for (int am = 0; am < 8; ++am) {
      long row = bm + wm * 128 + am * 16 + g * 4;
#pragma unroll
      for (int an = 0; an < 4; ++an) {
        long col = bn + wn * 64 + an * 16 + lr;
#pragma unroll
        for (int r = 0; r < 4; ++r)
          ((float*)Cout)[(row + r) * N + col] = acc[am][an][r];
      }
    }
  } else {
    // rope-Q epilogue: pair (d even/odd) sits in adjacent lanes -> __shfl_xor(v,1)
    const float scq = 0.12751743f;  // log2(e)/sqrt(128): softmax in exp2 domain
#pragma unroll
    for (int am = 0; am < 8; ++am) {
      int row0 = (int)bm + wm * 128 + am * 16 + g * 4;
      int s0 = row0 & (SEQ - 1);
      int bb = row0 >> 11;
#pragma unroll
      for (int an = 0; an < 4; ++an) {
        int col = (int)bn + wn * 64 + an * 16 + lr;  // < 4096 (Q launch)
        float bv = bias[col];
        int h = col >> 7, d = col & 127;
        const int odd = lr & 1;
#pragma unroll
        for (int r = 0; r < 4; ++r) {
          float v = acc[am][an][r] + bv;
          float p = __shfl_xor(v, 1);
          float2 cs = *(const float2*)&cache[((long)(s0 + r) * 64 + (d >> 1)) * 2];
          float o = odd ? (v * cs.x + p * cs.y) : (v * cs.x - p * cs.y);
          Qb[((long)(bb * NH + h) * SEQ + s0 + r) * HD + d] = (short)f2bf(o * scq);
        }
      }
    }
  }
}

// ================= 256x128 GEMM for the K/V columns (256 blocks = 1 full round) ======
#define KV_LDA(MSB, DB, KS)                                                      \
  { _Pragma("unroll") for (int mf = 0; mf < 4; ++mf)                             \
      af[mf] = *(const s16x8*)&lds[(MSB) + (DB) * 8192 + aoff[mf][KS]]; }
#define KV_LDB(DB, KS)                                                           \
  { _Pragma("unroll") for (int nf = 0; nf < 2; ++nf)                             \
      bfk[nf] = *(const s16x8*)&lds[32768 + (DB) * 8192 + boff[nf][KS]]; }
#define KV_MF(MS)                                                                \
  { _Pragma("unroll") for (int mf = 0; mf < 4; ++mf)                             \
      _Pragma("unroll") for (int nf = 0; nf < 2; ++nf)                           \
        acc[(MS) * 4 + mf][nf] = __builtin_amdgcn_mfma_f32_16x16x32_bf16(        \
            af[mf], bfk[nf], acc[(MS) * 4 + mf][nf], 0, 0, 0); }
#define KV_SA0(DB, KB) { gload16(sA0 + (KB), &lds[(DB) * 8192 + du0]);                 \
                         gload16(sA1 + (KB), &lds[(DB) * 8192 + du1]); }
#define KV_SA1(DB, KB) { gload16(sA0 + 64 * (long)HH + (KB), &lds[16384 + (DB) * 8192 + du0]); \
                         gload16(sA1 + 64 * (long)HH + (KB), &lds[16384 + (DB) * 8192 + du1]); }
#define KV_SB(DB, KB)  { gload16(sB0 + (KB), &lds[32768 + (DB) * 8192 + du0]);         \
                         gload16(sB1 + (KB), &lds[32768 + (DB) * 8192 + du1]); }

#define KVTILE(DB, KBS)                                                          \
  KV_LDA(0, DB, 0); KV_LDB(DB, 0);                                               \
  KV_SA0(DB ^ 1, KBS);                                                           \
  BARRIER;                                                                       \
  PRIO1; KV_MF(0); PRIO0;                                                        \
  asm volatile("s_waitcnt vmcnt(2)" ::: "memory");                               \
  BARRIER;                                                                       \
  KV_LDA(16384, DB, 0);                                                          \
  KV_SB(DB ^ 1, KBS);                                                            \
  BARRIER;                                                                       \
  PRIO1; KV_MF(1); PRIO0;                                                        \
  BARRIER;                                                                       \
  KV_LDA(16384, DB, 1); KV_LDB(DB, 1);                                           \
  KV_SA1(DB ^ 1, KBS);                                                           \
  BARRIER;                                                                       \
  PRIO1; KV_MF(1); PRIO0;                                                        \
  BARRIER;                                                                       \
  KV_LDA(0, DB, 1);                                                              \
  BARRIER;                                                                       \
  PRIO1; KV_MF(0); PRIO0;                                                        \
  asm volatile("s_waitcnt vmcnt(2)" ::: "memory");                               \
  BARRIER;

__global__ __launch_bounds__(512, 1) void gemm_kv(const short* __restrict__ A,
                                                  const short* __restrict__ Bt,
                                                  const float* __restrict__ bias,
                                                  const float* __restrict__ cache,
                                                  short* __restrict__ Kb,
                                                  short* __restrict__ Vtb) {
  extern __shared__ short lds[];
  const int t = threadIdx.x;
  const int lane = t & 63, w = t >> 6;
  const int g = lane >> 4, lr = lane & 15;
  const int wm = w >> 2, wn = w & 3;  // 2m x 4n waves; wave owns 128m x 32n
  const long bm = (long)blockIdx.y * 256;
  const int bnl = blockIdx.x * 128;   // local col in [0,2048)

  const short *sA0, *sA1, *sB0, *sB1;
  {
    int c0 = t, c1 = t + 512;
    int h0 = c0 >> 9, r0 = (c0 >> 3) & 63, tc0 = (c0 & 7) ^ (r0 & 7);
    int h1 = c1 >> 9, r1 = (c1 >> 3) & 63, tc1 = (c1 & 7) ^ (r1 & 7);
    sA0 = A + (bm + h0 * 128 + r0) * (long)HH + tc0 * 8;
    sA1 = A + (bm + h1 * 128 + r1) * (long)HH + tc1 * 8;
    int rb0 = c0 >> 3, tb0 = (c0 & 7) ^ (rb0 & 7);  // rows 0..63
    int rb1 = c1 >> 3, tb1 = (c1 & 7) ^ (rb1 & 7);  // rows 64..127
    sB0 = Bt + ((long)bnl + rb0) * HH + tb0 * 8;
    sB1 = Bt + ((long)bnl + rb1) * HH + tb1 * 8;
  }
  const int du0 = w * 512;
  const int du1 = w * 512 + 4096;

  int aoff[4][2], boff[2][2];
#pragma unroll
  for (int mf = 0; mf < 4; ++mf)
#pragma unroll
    for (int ks = 0; ks < 2; ++ks)
      aoff[mf][ks] = wm * 4096 + (mf * 16 + lr) * 64 + (((ks * 4 + g) ^ (lr & 7)) * 8);
#pragma unroll
  for (int nf = 0; nf < 2; ++nf)
#pragma unroll
    for (int ks = 0; ks < 2; ++ks)
      boff[nf][ks] = wn * 2048 + (nf * 16 + lr) * 64 + (((ks * 4 + g) ^ (lr & 7)) * 8);

  f32x4 acc[8][2] = {};
  s16x8 af[4], bfk[2];

  KV_SA0(0, 0); KV_SB(0, 0); KV_SA1(0, 0);
  asm volatile("s_waitcnt vmcnt(0)" ::: "memory");
  BARRIER;

  for (int kt = 0; kt < 64; kt += 2) {
    const long kb1 = (long)(kt + 1) * 64;
    const long kb2 = (kt + 2 < 64) ? (long)(kt + 2) * 64 : 0l;
    KVTILE(0, kb1);
    KVTILE(1, kb2);
  }

  // epilogue: cols 4096+bnl+... ; K region (cl<1024): rope; V region: transposed store
#pragma unroll
  for (int am = 0; am < 8; ++am) {
    int row0 = (int)bm + wm * 128 + am * 16 + g * 4;
    int s0 = row0 & (SEQ - 1);
    int bb = row0 >> 11;
#pragma unroll
    for (int an = 0; an < 2; ++an) {
      int cl = bnl + wn * 32 + an * 16 + lr;  // [0,2048), block-uniform region
      float bv = bias[4096 + cl];
      if (cl < 1024) {  // K: rope (unscaled)
        int gi = cl >> 7, d = cl & 127;
        const int odd = lr & 1;
#pragma unroll
        for (int r = 0; r < 4; ++r) {
          float v = acc[am][an][r] + bv;
          float p = __shfl_xor(v, 1);
          float2 cs = *(const float2*)&cache[((long)(s0 + r) * 64 + (d >> 1)) * 2];
          float o = odd ? (v * cs.x + p * cs.y) : (v * cs.x - p * cs.y);
          Kb[((long)(bb * NG + gi) * SEQ + s0 + r) * HD + d] = (short)f2bf(o);
        }
      } else {  // V: write directly transposed (4 consecutive s -> one s16x4)
        int cv = cl - 1024;
        int gi = cv >> 7, d = cv & 127;
        s16x4 o;
#pragma unroll
        for (int r = 0; r < 4; ++r) o[r] = (short)f2bf(acc[am][an][r] + bv);
        *(s16x4*)&Vtb[((long)(bb * NG + gi) * HD + d) * SEQ + s0] = o;
      }
    }
  }
}

// ---------------- causal GQA flash attention v4c: 8 waves, 32x32 MFMA ----------------
// R8: (1) KV L2-grouping: bid -> (b,kvh,hh,qt) with bid%8 == kvh, so all 32 blocks
// sharing one KV set land on one XCD (2 sets x 1MB in 4MB L2); adjacent bids have
// qt summing to 7 (pair-balanced). (2) P-pack via v_permlane32_swap_b32 (vdst.hi <->
// vsrc.lo): swap(w0,w2) yields pw0=[w0|sw2], pw2=[sw0|w2]; swap(w1,w3) likewise --
// replaces 16 ds_bpermute shfls + selects (LDS pipe, which is the attn bottleneck:
// ~41us of ds_read_b128 + ~8us of bpermute vs 7us MFMA). (3) setprio restored (R4).
__global__ __launch_bounds__(512, 1) void attn(const short* __restrict__ Qb,
                                               const short* __restrict__ Kb,
                                               const short* __restrict__ Vtb,
                                               short* __restrict__ Ob) {
  extern __shared__ short alds[];
  const int t = threadIdx.x, lane = t & 63, w = t >> 6;
  const int l31 = lane & 31, hi = lane >> 5;
  const int bid = (int)blockIdx.x;
  const int gg = bid & 15;        // KV group; bid%8 = kvh -> fixed XCD per group
  const int j  = bid >> 4;        // [0,32)
  const int p_ = j & 1;
  const int a_ = j >> 1;          // [0,16)
  const int q0 = a_ & 7;
  const int h2 = a_ >> 3;         // 0..1
  const int qt = p_ ? 7 - q0 : q0;
  const int b  = gg >> 3;         // batch
  const int h  = (gg & 7) * 4 + h2 * 2 + p_;  // query head
  const int qb = qt * 256;
  const short* Qhead = Qb + (long)(b * NH + h) * SEQ * HD;
  const short* Khead = Kb + (long)(b * NG + (h >> 2)) * SEQ * HD;
  const short* Vthead = Vtb + (long)(b * NG + (h >> 2)) * SEQ * HD;
  const int qw0 = qb + w * 32;     // wave's first q-row
  const int qrow = qw0 + l31;      // this lane's q (softmax state)
  float* facs = (float*)&alds[32768] + w * 32;

  s16x8 qf[8];
#pragma unroll
  for (int ds = 0; ds < 8; ++ds)
    qf[ds] = *(const s16x8*)&Qhead[(long)qrow * HD + ds * 16 + hi * 8];

  const short *kp0, *kp1, *vp0, *vp1;
  {
    int c0 = t, c1 = t + 512;
    int kr0 = c0 >> 4, kc0 = (c0 & 15) ^ (kr0 & 15);
    int kr1 = c1 >> 4, kc1 = (c1 & 15) ^ (kr1 & 15);
    kp0 = Khead + (long)kr0 * HD + kc0 * 8;
    kp1 = Khead + (long)kr1 * HD + kc1 * 8;
    int vr0 = c0 >> 3, vc0 = (c0 & 7) ^ (vr0 & 7);
    int vr1 = c1 >> 3, vc1 = (c1 & 7) ^ (vr1 & 7);
    vp0 = Vthead + (long)vr0 * SEQ + vc0 * 8;
    vp1 = Vthead + (long)vr1 * SEQ + vc1 * 8;
  }
  const int d0 = w * 512, d1 = w * 512 + 4096;

  f32x16 ao[4] = {};
  float mrun = -1.0e30f, lrun = 0.0f;
  const int nkt = 4 * qt + 4;

  gload16(kp0, &alds[d0]); gload16(kp1, &alds[d1]);
  gload16(vp0, &alds[16384 + d0]); gload16(vp1, &alds[16384 + d1]);
  kp0 += 64 * HD; kp1 += 64 * HD; vp0 += 64; vp1 += 64;
  asm volatile("s_waitcnt vmcnt(0)" ::: "memory");
  BARRIER;

  for (int kt = 0; kt < nkt; ++kt) {
    const int buf = kt & 1, nb = buf ^ 1;
    const int kb = kt * 64;
    const int bK = buf * 8192, bV = 16384 + buf * 8192;
    if (kt + 1 < nkt) {
      gload16(kp0, &alds[nb * 8192 + d0]); gload16(kp1, &alds[nb * 8192 + d1]);
      gload16(vp0, &alds[16384 + nb * 8192 + d0]); gload16(vp1, &alds[16384 + nb * 8192 + d1]);
      kp0 += 64 * HD; kp1 += 64 * HD; vp0 += 64; vp1 += 64;
    }
    if (kb <= qw0 + 31) {
      f32x16 st0 = {}, st1 = {};
      PRIO1;
#pragma unroll
      for (int ds = 0; ds < 8; ++ds) {
        const int c = ds * 2 + hi;
        const int r0 = l31, r1 = 32 + l31;
        s16x8 kf0 = *(const s16x8*)&alds[bK + r0 * 128 + ((c ^ (r0 & 15)) * 8)];
        s16x8 kf1 = *(const s16x8*)&alds[bK + r1 * 128 + ((c ^ (r1 & 15)) * 8)];
        st0 = __builtin_amdgcn_mfma_f32_32x32x16_bf16(kf0, qf[ds], st0, 0, 0, 0);
        st1 = __builtin_amdgcn_mfma_f32_32x32x16_bf16(kf1, qf[ds], st1, 0, 0, 0);
      }
      PRIO0;

      float p[32];
      if (kb + 63 > qrow || kb + 63 > qw0) {
#pragma unroll
        for (int r = 0; r < 16; ++r) {
          int kg = kb + (r & 3) + 8 * (r >> 2) + 4 * hi;
          p[r] = (kg > qrow) ? -1.0e30f : st0[r];
          p[16 + r] = (kg + 32 > qrow) ? -1.0e30f : st1[r];
        }
      } else {
#pragma unroll
        for (int r = 0; r < 16; ++r) { p[r] = st0[r]; p[16 + r] = st1[r]; }
      }
      // tree max (depth 5)
      float tt[16];
#pragma unroll
      for (int i = 0; i < 16; ++i) tt[i] = fmaxf(p[i], p[i + 16]);
#pragma unroll
      for (int s = 8; s >= 1; s >>= 1)
#pragma unroll
        for (int i = 0; i < 8; ++i)
          if (i < s) tt[i] = fmaxf(tt[i], tt[i + s]);
      float tmax = tt[0];
      tmax = fmaxf(tmax, __shfl_xor(tmax, 32));
      if (!__all(tmax <= mrun + 8.0f)) {
        float mnew = fmaxf(mrun, tmax);
        float fac = exp2f(mrun - mnew);
        facs[l31] = fac;
        mrun = mnew; lrun *= fac;
        f32x4 f0 = *(f32x4*)&facs[0 + 4 * hi];
        f32x4 f1 = *(f32x4*)&facs[8 + 4 * hi];
        f32x4 f2 = *(f32x4*)&facs[16 + 4 * hi];
        f32x4 f3 = *(f32x4*)&facs[24 + 4 * hi];
#pragma unroll
        for (int j2 = 0; j2 < 4; ++j2)
#pragma unroll
          for (int dt = 0; dt < 4; ++dt) {
            ao[dt][j2] *= f0[j2]; ao[dt][4 + j2] *= f1[j2];
            ao[dt][8 + j2] *= f2[j2]; ao[dt][12 + j2] *= f3[j2];
          }
      }
#pragma unroll
      for (int i = 0; i < 32; ++i) p[i] = exp2f(p[i] - mrun);
      // tree sum (depth 5)
      float ss[16];
#pragma unroll
      for (int i = 0; i < 16; ++i) ss[i] = p[i] + p[i + 16];
#pragma unroll
      for (int s = 8; s >= 1; s >>= 1)
#pragma unroll
        for (int i = 0; i < 8; ++i)
          if (i < s) ss[i] = ss[i] + ss[i + s];
      float tsum = ss[0];
      lrun += tsum + __shfl_xor(tsum, 32);

      // ---- pack P -> PV A-fragments via permlane32_swap (vdst.hi <-> vsrc.lo)
      // target: pw0=[w0|sw2], pw1=[w1|sw3], pw2=[sw0|w2], pw3=[sw1|w3]
      s16x8 pa[4];
#pragma unroll
      for (int ks = 0; ks < 4; ++ks) {
        unsigned w0, w1, w2, w3;
        asm("v_cvt_pk_bf16_f32 %0, %1, %2" : "=v"(w0) : "v"(p[ks * 8 + 0]), "v"(p[ks * 8 + 1]));
        asm("v_cvt_pk_bf16_f32 %0, %1, %2" : "=v"(w1) : "v"(p[ks * 8 + 2]), "v"(p[ks * 8 + 3]));
        asm("v_cvt_pk_bf16_f32 %0, %1, %2" : "=v"(w2) : "v"(p[ks * 8 + 4]), "v"(p[ks * 8 + 5]));
        asm("v_cvt_pk_bf16_f32 %0, %1, %2" : "=v"(w3) : "v"(p[ks * 8 + 6]), "v"(p[ks * 8 + 7]));
        asm("v_permlane32_swap_b32 %0, %1" : "+v"(w0), "+v"(w2));
        asm("v_permlane32_swap_b32 %0, %1" : "+v"(w1), "+v"(w3));
        u32x4 pw;
        pw[0] = w0; pw[1] = w1; pw[2] = w2; pw[3] = w3;
        pa[ks] = __builtin_bit_cast(s16x8, pw);
      }

      PRIO1;
#pragma unroll
      for (int ks = 0; ks < 4; ++ks)
#pragma unroll
        for (int dt = 0; dt < 4; ++dt) {
          int dd = dt * 32 + l31;
          int slot = (ks * 2 + hi) ^ (dd & 7);
          s16x8 vf = *(const s16x8*)&alds[bV + dd * 64 + slot * 8];
          ao[dt] = __builtin_amdgcn_mfma_f32_32x32x16_bf16(pa[ks], vf, ao[dt], 0, 0, 0);
        }
      PRIO0;
    }
    asm volatile("s_waitcnt vmcnt(0)" ::: "memory");
    BARRIER;
  }

  facs[l31] = 1.0f / lrun;
  float invr[16];
  {
    f32x4 i0 = *(f32x4*)&facs[0 + 4 * hi];
    f32x4 i1 = *(f32x4*)&facs[8 + 4 * hi];
    f32x4 i2 = *(f32x4*)&facs[16 + 4 * hi];
    f32x4 i3 = *(f32x4*)&facs[24 + 4 * hi];
#pragma unroll
    for (int j2 = 0; j2 < 4; ++j2) {
      invr[j2] = i0[j2]; invr[4 + j2] = i1[j2]; invr[8 + j2] = i2[j2]; invr[12 + j2] = i3[j2];
    }
  }
#pragma unroll
  for (int dt = 0; dt < 4; ++dt)
#pragma unroll
    for (int r = 0; r < 16; ++r) {
      int grow = qw0 + (r & 3) + 8 * (r >> 2) + 4 * hi;
      Ob[((long)b * SEQ + grow) * HH + h * HD + dt * 32 + l31] = (short)f2bf(ao[dt][r] * invr[r]);
    }
}

// ---------------- launch ----------------
extern "C" void kernel_launch(void* const* d_in, const int* in_sizes, int n_in,
                              void* d_out, int out_size, void* d_ws, size_t ws_size,
                              hipStream_t stream) {
  const float* x     = (const float*)d_in[0];
  const float* cache = (const float*)d_in[1];
  const float* Wqkv  = (const float*)d_in[2];
  const float* bqkv  = (const float*)d_in[3];
  const float* Wd    = (const float*)d_in[4];

  char* ws = (char*)d_ws;
  short* xb   = (short*)(ws);                       // [BS][H]        32MB
  short* wqt  = (short*)(ws + 33554432ll);          // [NQKV][H]      48MB
  short* wdt  = (short*)(ws + 83886080ll);          // [H][H]         32MB
  short* Qb   = (short*)(ws + 167772160ll);         // [B*NH][S][HD]  32MB
  short* Kb   = (short*)(ws + 201326592ll);         // [B*NG][S][HD]   8MB
  short* Vtb  = (short*)(ws + 218103808ll);         // [B*NG][HD][S]   8MB
  short* Ob   = (short*)(ws + 226492416ll);         // [BS][H]        32MB

  cast_f32_bf16<<<2048, 256, 0, stream>>>(x, xb, (long)BS * HH / 4);
  transpose_cast<<<dim3(NQKV / 32, HH / 32), 256, 0, stream>>>(Wqkv, wqt, HH, NQKV);
  transpose_cast<<<dim3(HH / 32, HH / 32), 256, 0, stream>>>(Wd, wdt, HH, HH);
  // Q projection: 256 blocks = 1 full round, fused rope-Q epilogue
  gemm256<2><<<dim3(16, 16), 512, 131072, stream>>>(
      xb, wqt, bqkv, nullptr, cache, Qb, BS, HH, HH);
  // K/V projection: 256x128 tiles -> 256 blocks = 1 full round at half work
  gemm_kv<<<dim3(16, 16), 512, 98304, stream>>>(
      xb, wqt + 4096ll * HH, bqkv, cache, Kb, Vtb);
  attn<<<512, 512, 66560, stream>>>(Qb, Kb, Vtb, Ob);
  gemm256<0><<<dim3(16, 16), 512, 131072, stream>>>(
      Ob, wdt, nullptr, d_out, nullptr, nullptr, BS, HH, HH);
}

// Round 9
// 477.641 us; speedup vs baseline: 1.1075x; 1.1075x over previous
//
#include <hip/hip_runtime.h>
#include <hip/hip_bf16.h>
#include <math.h>

#define BS   4096   // B*S
#define HH   4096   // hidden
#define NH   32
#define NG   8
#define HD   128
#define SEQ  2048
#define NQKV 6144   // H + 2*NG*HD

typedef float f32x4 __attribute__((ext_vector_type(4)));
typedef float f32x16 __attribute__((ext_vector_type(16)));
typedef short s16x8 __attribute__((ext_vector_type(8)));
typedef short s16x4 __attribute__((ext_vector_type(4)));
typedef unsigned int u32x4 __attribute__((ext_vector_type(4)));

__device__ __forceinline__ unsigned short f2bf(float f) {
  unsigned int u = __builtin_bit_cast(unsigned int, f);
  unsigned int r = (u + 0x7fffu + ((u >> 16) & 1u)) >> 16;
  return (unsigned short)r;
}
__device__ __forceinline__ float b2f(short h) {
  unsigned int u = ((unsigned int)(unsigned short)h) << 16;
  return __builtin_bit_cast(float, u);
}

// async global->LDS, 16B per lane; lds base must be wave-uniform (HW adds lane*16)
__device__ __forceinline__ void gload16(const void* g, void* l) {
  __builtin_amdgcn_global_load_lds((__attribute__((address_space(1))) void*)(g),
                                   (__attribute__((address_space(3))) void*)(l), 16, 0, 0);
}

#define BARRIER __builtin_amdgcn_s_barrier()
#define PRIO1 __builtin_amdgcn_s_setprio(1)
#define PRIO0 __builtin_amdgcn_s_setprio(0)

// ---------------- cast fp32 -> bf16 (vectorized) ----------------
__global__ void cast_f32_bf16(const float* __restrict__ in, short* __restrict__ out, long n4) {
  long i = (long)blockIdx.x * blockDim.x + threadIdx.x;
  long stride = (long)gridDim.x * blockDim.x;
  for (; i < n4; i += stride) {
    float4 v = *(const float4*)&in[i * 4];
    s16x4 o;
    o[0] = (short)f2bf(v.x); o[1] = (short)f2bf(v.y);
    o[2] = (short)f2bf(v.z); o[3] = (short)f2bf(v.w);
    *(s16x4*)&out[i * 4] = o;
  }
}

// ---------------- transpose + cast: in f32 [R][C] -> out bf16 [C][R] ----------------
// R4 scalar-store version (R7 vectorization measured null: HBM-bound).
__global__ __launch_bounds__(256) void transpose_cast(const float* __restrict__ in,
                                                      short* __restrict__ out, int R, int C) {
  __shared__ float tile[32][33];
  int tx = threadIdx.x & 31, ty = threadIdx.x >> 5;  // ty 0..7
  long c0 = (long)blockIdx.x * 32, r0 = (long)blockIdx.y * 32;
#pragma unroll
  for (int j = 0; j < 32; j += 8)
    tile[ty + j][tx] = in[(r0 + ty + j) * C + c0 + tx];
  __syncthreads();
#pragma unroll
  for (int j = 0; j < 32; j += 8)
    out[(c0 + ty + j) * R + r0 + tx] = (short)f2bf(tile[tx][ty + j]);
}

// ================= 256x256 8-phase GEMM (R4 schedule: proven best, 128.6us) =================
// FROZEN. R2 flattening and R5 deep-staging both regressed; local optimum (~46 MfmaUtil).
#define LDA_FR(BASE, DB)                                                         \
  {                                                                              \
    _Pragma("unroll") for (int mf = 0; mf < 4; ++mf)                             \
      _Pragma("unroll") for (int ks = 0; ks < 2; ++ks)                           \
        af[mf][ks] = *(const s16x8*)&lds[(BASE) + (DB) * 8192 + aoff[mf][ks]];   \
  }
#define LDB_FR(BASE, DB)                                                         \
  {                                                                              \
    _Pragma("unroll") for (int nf = 0; nf < 2; ++nf)                             \
      _Pragma("unroll") for (int ks = 0; ks < 2; ++ks)                           \
        bf[nf][ks] = *(const s16x8*)&lds[(BASE) + (DB) * 8192 + boff[nf][ks]];   \
  }
#define MF_Q(MS, NS)                                                             \
  {                                                                              \
    _Pragma("unroll") for (int ks = 0; ks < 2; ++ks)                             \
      _Pragma("unroll") for (int mf = 0; mf < 4; ++mf)                           \
        _Pragma("unroll") for (int nf = 0; nf < 2; ++nf)                         \
          acc[(MS) * 4 + mf][(NS) * 2 + nf] = __builtin_amdgcn_mfma_f32_16x16x32_bf16( \
              af[mf][ks], bf[nf][ks], acc[(MS) * 4 + mf][(NS) * 2 + nf], 0, 0, 0);     \
  }
#define STG_AU0(DB, KB) { gload16(sA0 + (KB), &lds[0 + (DB) * 8192 + du0]);            \
                          gload16(sA1 + (KB), &lds[0 + (DB) * 8192 + du1]); }
#define STG_BU0(DB, KB) { gload16(sB0 + (KB), &lds[32768 + (DB) * 8192 + du0]);        \
                          gload16(sB1 + (KB), &lds[32768 + (DB) * 8192 + du1]); }
#define STG_AU1(DB, KB) { gload16(sA0 + 64 * (long)K + (KB), &lds[16384 + (DB) * 8192 + du0]); \
                          gload16(sA1 + 64 * (long)K + (KB), &lds[16384 + (DB) * 8192 + du1]); }
#define STG_BU1(DB, KB) { gload16(sB0 + 32 * (long)K + (KB), &lds[49152 + (DB) * 8192 + du0]); \
                          gload16(sB1 + 32 * (long)K + (KB), &lds[49152 + (DB) * 8192 + du1]); }

#define TILE256(DB, KBS)                                                         \
  LDA_FR(0, DB); LDB_FR(32768, DB);                                              \
  STG_AU0(DB ^ 1, KBS); STG_BU0(DB ^ 1, KBS);                                    \
  BARRIER;                                                                       \
  PRIO1; MF_Q(0, 0); PRIO0;                                                      \
  asm volatile("s_waitcnt vmcnt(6)" ::: "memory");                               \
  BARRIER;                                                                       \
  LDB_FR(49152, DB);                                                             \
  STG_BU1(DB ^ 1, KBS);                                                          \
  BARRIER;                                                                       \
  PRIO1; MF_Q(0, 1); PRIO0;                                                      \
  asm volatile("s_waitcnt vmcnt(6)" ::: "memory");                               \
  BARRIER;                                                                       \
  LDA_FR(16384, DB);                                                             \
  STG_AU1(DB ^ 1, KBS);                                                          \
  BARRIER;                                                                       \
  PRIO1; MF_Q(1, 1); PRIO0;                                                      \
  BARRIER;                                                                       \
  LDB_FR(32768, DB);                                                             \
  BARRIER;                                                                       \
  PRIO1; MF_Q(1, 0); PRIO0;                                                      \
  asm volatile("s_waitcnt vmcnt(4)" ::: "memory");                               \
  BARRIER;

// MODE 0: plain f32 output, no bias (dense projection)
// MODE 2: fused rope-Q epilogue (N=4096 launch: all cols are Q; scaled, log2e folded)
template <int MODE>
__global__ __launch_bounds__(512, 1) void gemm256(const short* __restrict__ A,
                                                  const short* __restrict__ Bt,
                                                  const float* __restrict__ bias,
                                                  void* __restrict__ Cout,
                                                  const float* __restrict__ cache,
                                                  short* __restrict__ Qb,
                                                  int M, int N, int K) {
  extern __shared__ short lds[];
  const int t = threadIdx.x;
  const int lane = t & 63, w = t >> 6;
  const int g = lane >> 4, lr = lane & 15;
  const int wm = w >> 2, wn = w & 3;  // 2 x 4 wave grid
  const long bm = (long)blockIdx.y * 256;
  const long bn = (long)blockIdx.x * 256;

  const short *sA0, *sA1, *sB0, *sB1;
  {
    int c0 = t, c1 = t + 512;
    int h0 = c0 >> 9, r0 = (c0 >> 3) & 63, tc0 = (c0 & 7) ^ (r0 & 7);
    int h1 = c1 >> 9, r1 = (c1 >> 3) & 63, tc1 = (c1 & 7) ^ (r1 & 7);
    sA0 = A + (bm + h0 * 128 + r0) * (long)K + tc0 * 8;
    sA1 = A + (bm + h1 * 128 + r1) * (long)K + tc1 * 8;
    int g0 = c0 >> 8, rb0 = (c0 >> 3) & 31, tb0 = (c0 & 7) ^ (rb0 & 7);
    int g1 = c1 >> 8, rb1 = (c1 >> 3) & 31, tb1 = (c1 & 7) ^ (rb1 & 7);
    sB0 = Bt + (bn + g0 * 64 + rb0) * (long)K + tb0 * 8;
    sB1 = Bt + (bn + g1 * 64 + rb1) * (long)K + tb1 * 8;
  }
  const int du0 = w * 512;
  const int du1 = w * 512 + 4096;

  int aoff[4][2], boff[2][2];
#pragma unroll
  for (int mf = 0; mf < 4; ++mf)
#pragma unroll
    for (int ks = 0; ks < 2; ++ks)
      aoff[mf][ks] = wm * 4096 + (mf * 16 + lr) * 64 + (((ks * 4 + g) ^ (lr & 7)) * 8);
#pragma unroll
  for (int nf = 0; nf < 2; ++nf)
#pragma unroll
    for (int ks = 0; ks < 2; ++ks)
      boff[nf][ks] = wn * 2048 + (nf * 16 + lr) * 64 + (((ks * 4 + g) ^ (lr & 7)) * 8);

  f32x4 acc[8][4] = {};
  s16x8 af[4][2], bf[2][2];

  STG_AU0(0, 0); STG_BU0(0, 0); STG_AU1(0, 0); STG_BU1(0, 0);
  asm volatile("s_waitcnt vmcnt(0)" ::: "memory");
  BARRIER;

  const int NT = K >> 6;
  for (int kt = 0; kt < NT; kt += 2) {
    const long kb1 = (long)(kt + 1) * 64;
    const long kb2 = (kt + 2 < NT) ? (long)(kt + 2) * 64 : 0l;
    TILE256(0, kb1);
    TILE256(1, kb2);
  }

  if (MODE == 0) {
#pragma unroll
    for (int am = 0; am < 8; ++am) {
      long row = bm + wm * 128 + am * 16 + g * 4;
#pragma unroll
      for (int an = 0; an < 4; ++an) {
        long col = bn + wn * 64 + an * 16 + lr;
#pragma unroll
        for (int r = 0; r < 4; ++r)
          ((float*)Cout)[(row + r) * N + col] = acc[am][an][r];
      }
    }
  } else {
    // rope-Q epilogue: pair (d even/odd) sits in adjacent lanes -> __shfl_xor(v,1)
    const float scq = 0.12751743f;  // log2(e)/sqrt(128): softmax in exp2 domain
#pragma unroll
    for (int am = 0; am < 8; ++am) {
      int row0 = (int)bm + wm * 128 + am * 16 + g * 4;
      int s0 = row0 & (SEQ - 1);
      int bb = row0 >> 11;
#pragma unroll
      for (int an = 0; an < 4; ++an) {
        int col = (int)bn + wn * 64 + an * 16 + lr;  // < 4096 (Q launch)
        float bv = bias[col];
        int h = col >> 7, d = col & 127;
        const int odd = lr & 1;
#pragma unroll
        for (int r = 0; r < 4; ++r) {
          float v = acc[am][an][r] + bv;
          float p = __shfl_xor(v, 1);
          float2 cs = *(const float2*)&cache[((long)(s0 + r) * 64 + (d >> 1)) * 2];
          float o = odd ? (v * cs.x + p * cs.y) : (v * cs.x - p * cs.y);
          Qb[((long)(bb * NH + h) * SEQ + s0 + r) * HD + d] = (short)f2bf(o * scq);
        }
      }
    }
  }
}

// ================= 256x128 GEMM for the K/V columns (256 blocks = 1 full round) ======
#define KV_LDA(MSB, DB, KS)                                                      \
  { _Pragma("unroll") for (int mf = 0; mf < 4; ++mf)                             \
      af[mf] = *(const s16x8*)&lds[(MSB) + (DB) * 8192 + aoff[mf][KS]]; }
#define KV_LDB(DB, KS)                                                           \
  { _Pragma("unroll") for (int nf = 0; nf < 2; ++nf)                             \
      bfk[nf] = *(const s16x8*)&lds[32768 + (DB) * 8192 + boff[nf][KS]]; }
#define KV_MF(MS)                                                                \
  { _Pragma("unroll") for (int mf = 0; mf < 4; ++mf)                             \
      _Pragma("unroll") for (int nf = 0; nf < 2; ++nf)                           \
        acc[(MS) * 4 + mf][nf] = __builtin_amdgcn_mfma_f32_16x16x32_bf16(        \
            af[mf], bfk[nf], acc[(MS) * 4 + mf][nf], 0, 0, 0); }
#define KV_SA0(DB, KB) { gload16(sA0 + (KB), &lds[(DB) * 8192 + du0]);                 \
                         gload16(sA1 + (KB), &lds[(DB) * 8192 + du1]); }
#define KV_SA1(DB, KB) { gload16(sA0 + 64 * (long)HH + (KB), &lds[16384 + (DB) * 8192 + du0]); \
                         gload16(sA1 + 64 * (long)HH + (KB), &lds[16384 + (DB) * 8192 + du1]); }
#define KV_SB(DB, KB)  { gload16(sB0 + (KB), &lds[32768 + (DB) * 8192 + du0]);         \
                         gload16(sB1 + (KB), &lds[32768 + (DB) * 8192 + du1]); }

#define KVTILE(DB, KBS)                                                          \
  KV_LDA(0, DB, 0); KV_LDB(DB, 0);                                               \
  KV_SA0(DB ^ 1, KBS);                                                           \
  BARRIER;                                                                       \
  PRIO1; KV_MF(0); PRIO0;                                                        \
  asm volatile("s_waitcnt vmcnt(2)" ::: "memory");                               \
  BARRIER;                                                                       \
  KV_LDA(16384, DB, 0);                                                          \
  KV_SB(DB ^ 1, KBS);                                                            \
  BARRIER;                                                                       \
  PRIO1; KV_MF(1); PRIO0;                                                        \
  BARRIER;                                                                       \
  KV_LDA(16384, DB, 1); KV_LDB(DB, 1);                                           \
  KV_SA1(DB ^ 1, KBS);                                                           \
  BARRIER;                                                                       \
  PRIO1; KV_MF(1); PRIO0;                                                        \
  BARRIER;                                                                       \
  KV_LDA(0, DB, 1);                                                              \
  BARRIER;                                                                       \
  PRIO1; KV_MF(0); PRIO0;                                                        \
  asm volatile("s_waitcnt vmcnt(2)" ::: "memory");                               \
  BARRIER;

__global__ __launch_bounds__(512, 1) void gemm_kv(const short* __restrict__ A,
                                                  const short* __restrict__ Bt,
                                                  const float* __restrict__ bias,
                                                  const float* __restrict__ cache,
                                                  short* __restrict__ Kb,
                                                  short* __restrict__ Vtb) {
  extern __shared__ short lds[];
  const int t = threadIdx.x;
  const int lane = t & 63, w = t >> 6;
  const int g = lane >> 4, lr = lane & 15;
  const int wm = w >> 2, wn = w & 3;  // 2m x 4n waves; wave owns 128m x 32n
  const long bm = (long)blockIdx.y * 256;
  const int bnl = blockIdx.x * 128;   // local col in [0,2048)

  const short *sA0, *sA1, *sB0, *sB1;
  {
    int c0 = t, c1 = t + 512;
    int h0 = c0 >> 9, r0 = (c0 >> 3) & 63, tc0 = (c0 & 7) ^ (r0 & 7);
    int h1 = c1 >> 9, r1 = (c1 >> 3) & 63, tc1 = (c1 & 7) ^ (r1 & 7);
    sA0 = A + (bm + h0 * 128 + r0) * (long)HH + tc0 * 8;
    sA1 = A + (bm + h1 * 128 + r1) * (long)HH + tc1 * 8;
    int rb0 = c0 >> 3, tb0 = (c0 & 7) ^ (rb0 & 7);  // rows 0..63
    int rb1 = c1 >> 3, tb1 = (c1 & 7) ^ (rb1 & 7);  // rows 64..127
    sB0 = Bt + ((long)bnl + rb0) * HH + tb0 * 8;
    sB1 = Bt + ((long)bnl + rb1) * HH + tb1 * 8;
  }
  const int du0 = w * 512;
  const int du1 = w * 512 + 4096;

  int aoff[4][2], boff[2][2];
#pragma unroll
  for (int mf = 0; mf < 4; ++mf)
#pragma unroll
    for (int ks = 0; ks < 2; ++ks)
      aoff[mf][ks] = wm * 4096 + (mf * 16 + lr) * 64 + (((ks * 4 + g) ^ (lr & 7)) * 8);
#pragma unroll
  for (int nf = 0; nf < 2; ++nf)
#pragma unroll
    for (int ks = 0; ks < 2; ++ks)
      boff[nf][ks] = wn * 2048 + (nf * 16 + lr) * 64 + (((ks * 4 + g) ^ (lr & 7)) * 8);

  f32x4 acc[8][2] = {};
  s16x8 af[4], bfk[2];

  KV_SA0(0, 0); KV_SB(0, 0); KV_SA1(0, 0);
  asm volatile("s_waitcnt vmcnt(0)" ::: "memory");
  BARRIER;

  for (int kt = 0; kt < 64; kt += 2) {
    const long kb1 = (long)(kt + 1) * 64;
    const long kb2 = (kt + 2 < 64) ? (long)(kt + 2) * 64 : 0l;
    KVTILE(0, kb1);
    KVTILE(1, kb2);
  }

  // epilogue: cols 4096+bnl+... ; K region (cl<1024): rope; V region: transposed store
#pragma unroll
  for (int am = 0; am < 8; ++am) {
    int row0 = (int)bm + wm * 128 + am * 16 + g * 4;
    int s0 = row0 & (SEQ - 1);
    int bb = row0 >> 11;
#pragma unroll
    for (int an = 0; an < 2; ++an) {
      int cl = bnl + wn * 32 + an * 16 + lr;  // [0,2048), block-uniform region
      float bv = bias[4096 + cl];
      if (cl < 1024) {  // K: rope (unscaled)
        int gi = cl >> 7, d = cl & 127;
        const int odd = lr & 1;
#pragma unroll
        for (int r = 0; r < 4; ++r) {
          float v = acc[am][an][r] + bv;
          float p = __shfl_xor(v, 1);
          float2 cs = *(const float2*)&cache[((long)(s0 + r) * 64 + (d >> 1)) * 2];
          float o = odd ? (v * cs.x + p * cs.y) : (v * cs.x - p * cs.y);
          Kb[((long)(bb * NG + gi) * SEQ + s0 + r) * HD + d] = (short)f2bf(o);
        }
      } else {  // V: write directly transposed (4 consecutive s -> one s16x4)
        int cv = cl - 1024;
        int gi = cv >> 7, d = cv & 127;
        s16x4 o;
#pragma unroll
        for (int r = 0; r < 4; ++r) o[r] = (short)f2bf(acc[am][an][r] + bv);
        *(s16x4*)&Vtb[((long)(bb * NG + gi) * HD + d) * SEQ + s0] = o;
      }
    }
  }
}

// ---------------- causal GQA flash attention v4c: 8 waves, 32x32 MFMA ----------------
// R9 = R4-best attn (head-major map, setprio, serial reductions) with ONE isolated
// change: P-pack via v_permlane32_swap_b32 (semantics HW-verified in R8: absmax
// identical). R8's KV-grouping map is REVERTED: it co-located equal-qt blocks on
// CUs under every pairing model -> 64-unit tail CUs (attn 127->169us, +42).
__global__ __launch_bounds__(512, 1) void attn(const short* __restrict__ Qb,
                                               const short* __restrict__ Kb,
                                               const short* __restrict__ Vtb,
                                               short* __restrict__ Ob) {
  extern __shared__ short alds[];
  const int t = threadIdx.x, lane = t & 63, w = t >> 6;
  const int l31 = lane & 31, hi = lane >> 5;
  const int qt = 7 - (int)(blockIdx.x >> 6);   // heavy q-tiles first
  const int head = blockIdx.x & 63;
  const int b = head >> 5, h = head & 31;
  const int qb = qt * 256;
  const short* Qhead = Qb + (long)(b * NH + h) * SEQ * HD;
  const short* Khead = Kb + (long)(b * NG + (h >> 2)) * SEQ * HD;
  const short* Vthead = Vtb + (long)(b * NG + (h >> 2)) * SEQ * HD;
  const int qw0 = qb + w * 32;     // wave's first q-row
  const int qrow = qw0 + l31;      // this lane's q (softmax state)
  float* facs = (float*)&alds[32768] + w * 32;

  s16x8 qf[8];
#pragma unroll
  for (int ds = 0; ds < 8; ++ds)
    qf[ds] = *(const s16x8*)&Qhead[(long)qrow * HD + ds * 16 + hi * 8];

  const short *kp0, *kp1, *vp0, *vp1;
  {
    int c0 = t, c1 = t + 512;
    int kr0 = c0 >> 4, kc0 = (c0 & 15) ^ (kr0 & 15);
    int kr1 = c1 >> 4, kc1 = (c1 & 15) ^ (kr1 & 15);
    kp0 = Khead + (long)kr0 * HD + kc0 * 8;
    kp1 = Khead + (long)kr1 * HD + kc1 * 8;
    int vr0 = c0 >> 3, vc0 = (c0 & 7) ^ (vr0 & 7);
    int vr1 = c1 >> 3, vc1 = (c1 & 7) ^ (vr1 & 7);
    vp0 = Vthead + (long)vr0 * SEQ + vc0 * 8;
    vp1 = Vthead + (long)vr1 * SEQ + vc1 * 8;
  }
  const int d0 = w * 512, d1 = w * 512 + 4096;

  f32x16 ao[4] = {};
  float mrun = -1.0e30f, lrun = 0.0f;
  const int nkt = 4 * qt + 4;

  gload16(kp0, &alds[d0]); gload16(kp1, &alds[d1]);
  gload16(vp0, &alds[16384 + d0]); gload16(vp1, &alds[16384 + d1]);
  kp0 += 64 * HD; kp1 += 64 * HD; vp0 += 64; vp1 += 64;
  asm volatile("s_waitcnt vmcnt(0)" ::: "memory");
  BARRIER;

  for (int kt = 0; kt < nkt; ++kt) {
    const int buf = kt & 1, nb = buf ^ 1;
    const int kb = kt * 64;
    const int bK = buf * 8192, bV = 16384 + buf * 8192;
    if (kt + 1 < nkt) {
      gload16(kp0, &alds[nb * 8192 + d0]); gload16(kp1, &alds[nb * 8192 + d1]);
      gload16(vp0, &alds[16384 + nb * 8192 + d0]); gload16(vp1, &alds[16384 + nb * 8192 + d1]);
      kp0 += 64 * HD; kp1 += 64 * HD; vp0 += 64; vp1 += 64;
    }
    if (kb <= qw0 + 31) {
      f32x16 st0 = {}, st1 = {};
      PRIO1;
#pragma unroll
      for (int ds = 0; ds < 8; ++ds) {
        const int c = ds * 2 + hi;
        const int r0 = l31, r1 = 32 + l31;
        s16x8 kf0 = *(const s16x8*)&alds[bK + r0 * 128 + ((c ^ (r0 & 15)) * 8)];
        s16x8 kf1 = *(const s16x8*)&alds[bK + r1 * 128 + ((c ^ (r1 & 15)) * 8)];
        st0 = __builtin_amdgcn_mfma_f32_32x32x16_bf16(kf0, qf[ds], st0, 0, 0, 0);
        st1 = __builtin_amdgcn_mfma_f32_32x32x16_bf16(kf1, qf[ds], st1, 0, 0, 0);
      }
      PRIO0;

      float p[32];
      if (kb + 63 > qrow || kb + 63 > qw0) {
#pragma unroll
        for (int r = 0; r < 16; ++r) {
          int kg = kb + (r & 3) + 8 * (r >> 2) + 4 * hi;
          p[r] = (kg > qrow) ? -1.0e30f : st0[r];
          p[16 + r] = (kg + 32 > qrow) ? -1.0e30f : st1[r];
        }
      } else {
#pragma unroll
        for (int r = 0; r < 16; ++r) { p[r] = st0[r]; p[16 + r] = st1[r]; }
      }
      float tmax = -1.0e30f;
#pragma unroll
      for (int i = 0; i < 32; ++i) tmax = fmaxf(tmax, p[i]);
      tmax = fmaxf(tmax, __shfl_xor(tmax, 32));
      if (!__all(tmax <= mrun + 8.0f)) {
        float mnew = fmaxf(mrun, tmax);
        float fac = exp2f(mrun - mnew);
        facs[l31] = fac;
        mrun = mnew; lrun *= fac;
        f32x4 f0 = *(f32x4*)&facs[0 + 4 * hi];
        f32x4 f1 = *(f32x4*)&facs[8 + 4 * hi];
        f32x4 f2 = *(f32x4*)&facs[16 + 4 * hi];
        f32x4 f3 = *(f32x4*)&facs[24 + 4 * hi];
#pragma unroll
        for (int j = 0; j < 4; ++j)
#pragma unroll
          for (int dt = 0; dt < 4; ++dt) {
            ao[dt][j] *= f0[j]; ao[dt][4 + j] *= f1[j];
            ao[dt][8 + j] *= f2[j]; ao[dt][12 + j] *= f3[j];
          }
      }
      float tsum = 0.0f;
#pragma unroll
      for (int i = 0; i < 32; ++i) { p[i] = exp2f(p[i] - mrun); tsum += p[i]; }
      lrun += tsum + __shfl_xor(tsum, 32);

      // ---- pack P -> PV A-fragments via permlane32_swap (vdst.hi <-> vsrc.lo)
      // target: pw0=[w0|sw2], pw1=[w1|sw3], pw2=[sw0|w2], pw3=[sw1|w3]
      // (equivalent to the shfl_xor+select pack; verified exact in R8, absmax equal)
      s16x8 pa[4];
#pragma unroll
      for (int ks = 0; ks < 4; ++ks) {
        unsigned w0, w1, w2, w3;
        asm("v_cvt_pk_bf16_f32 %0, %1, %2" : "=v"(w0) : "v"(p[ks * 8 + 0]), "v"(p[ks * 8 + 1]));
        asm("v_cvt_pk_bf16_f32 %0, %1, %2" : "=v"(w1) : "v"(p[ks * 8 + 2]), "v"(p[ks * 8 + 3]));
        asm("v_cvt_pk_bf16_f32 %0, %1, %2" : "=v"(w2) : "v"(p[ks * 8 + 4]), "v"(p[ks * 8 + 5]));
        asm("v_cvt_pk_bf16_f32 %0, %1, %2" : "=v"(w3) : "v"(p[ks * 8 + 6]), "v"(p[ks * 8 + 7]));
        asm("v_permlane32_swap_b32 %0, %1" : "+v"(w0), "+v"(w2));
        asm("v_permlane32_swap_b32 %0, %1" : "+v"(w1), "+v"(w3));
        u32x4 pw;
        pw[0] = w0; pw[1] = w1; pw[2] = w2; pw[3] = w3;
        pa[ks] = __builtin_bit_cast(s16x8, pw);
      }

      PRIO1;
#pragma unroll
      for (int ks = 0; ks < 4; ++ks)
#pragma unroll
        for (int dt = 0; dt < 4; ++dt) {
          int dd = dt * 32 + l31;
          int slot = (ks * 2 + hi) ^ (dd & 7);
          s16x8 vf = *(const s16x8*)&alds[bV + dd * 64 + slot * 8];
          ao[dt] = __builtin_amdgcn_mfma_f32_32x32x16_bf16(pa[ks], vf, ao[dt], 0, 0, 0);
        }
      PRIO0;
    }
    asm volatile("s_waitcnt vmcnt(0)" ::: "memory");
    BARRIER;
  }

  facs[l31] = 1.0f / lrun;
  float invr[16];
  {
    f32x4 i0 = *(f32x4*)&facs[0 + 4 * hi];
    f32x4 i1 = *(f32x4*)&facs[8 + 4 * hi];
    f32x4 i2 = *(f32x4*)&facs[16 + 4 * hi];
    f32x4 i3 = *(f32x4*)&facs[24 + 4 * hi];
#pragma unroll
    for (int j = 0; j < 4; ++j) {
      invr[j] = i0[j]; invr[4 + j] = i1[j]; invr[8 + j] = i2[j]; invr[12 + j] = i3[j];
    }
  }
#pragma unroll
  for (int dt = 0; dt < 4; ++dt)
#pragma unroll
    for (int r = 0; r < 16; ++r) {
      int grow = qw0 + (r & 3) + 8 * (r >> 2) + 4 * hi;
      Ob[((long)b * SEQ + grow) * HH + h * HD + dt * 32 + l31] = (short)f2bf(ao[dt][r] * invr[r]);
    }
}

// ---------------- launch ----------------
extern "C" void kernel_launch(void* const* d_in, const int* in_sizes, int n_in,
                              void* d_out, int out_size, void* d_ws, size_t ws_size,
                              hipStream_t stream) {
  const float* x     = (const float*)d_in[0];
  const float* cache = (const float*)d_in[1];
  const float* Wqkv  = (const float*)d_in[2];
  const float* bqkv  = (const float*)d_in[3];
  const float* Wd    = (const float*)d_in[4];

  char* ws = (char*)d_ws;
  short* xb   = (short*)(ws);                       // [BS][H]        32MB
  short* wqt  = (short*)(ws + 33554432ll);          // [NQKV][H]      48MB
  short* wdt  = (short*)(ws + 83886080ll);          // [H][H]         32MB
  short* Qb   = (short*)(ws + 167772160ll);         // [B*NH][S][HD]  32MB
  short* Kb   = (short*)(ws + 201326592ll);         // [B*NG][S][HD]   8MB
  short* Vtb  = (short*)(ws + 218103808ll);         // [B*NG][HD][S]   8MB
  short* Ob   = (short*)(ws + 226492416ll);         // [BS][H]        32MB

  cast_f32_bf16<<<2048, 256, 0, stream>>>(x, xb, (long)BS * HH / 4);
  transpose_cast<<<dim3(NQKV / 32, HH / 32), 256, 0, stream>>>(Wqkv, wqt, HH, NQKV);
  transpose_cast<<<dim3(HH / 32, HH / 32), 256, 0, stream>>>(Wd, wdt, HH, HH);
  // Q projection: 256 blocks = 1 full round, fused rope-Q epilogue
  gemm256<2><<<dim3(16, 16), 512, 131072, stream>>>(
      xb, wqt, bqkv, nullptr, cache, Qb, BS, HH, HH);
  // K/V projection: 256x128 tiles -> 256 blocks = 1 full round at half work
  gemm_kv<<<dim3(16, 16), 512, 98304, stream>>>(
      xb, wqt + 4096ll * HH, bqkv, cache, Kb, Vtb);
  attn<<<512, 512, 66560, stream>>>(Qb, Kb, Vtb, Ob);
  gemm256<0><<<dim3(16, 16), 512, 131072, stream>>>(
      Ob, wdt, nullptr, d_out, nullptr, nullptr, BS, HH, HH);
}